// Round 5
// baseline (1034.502 us; speedup 1.0000x reference)
//
#include <hip/hip_runtime.h>
#include <hip/hip_bf16.h>

#define IN_C 128
#define HID_C 128
#define OUT_C 64

typedef unsigned short u16;
typedef unsigned int   u32;

// ---------------------------------------------------------------- utilities

__global__ void zero_kernel(int* __restrict__ p, int n) {
    int i = blockIdx.x * blockDim.x + threadIdx.x;
    if (i < n) p[i] = 0;
}

// out-degree histogram + coarse dst-bucket histogram (bucket = dst>>6)
__global__ void count_kernel(const int* __restrict__ src, const int* __restrict__ dst,
                             int* __restrict__ cnt_out, int* __restrict__ bcnt, int E) {
    for (int i = blockIdx.x * blockDim.x + threadIdx.x; i < E; i += gridDim.x * blockDim.x) {
        atomicAdd(&cnt_out[src[i]], 1);
        atomicAdd(&bcnt[dst[i] >> 6], 1);
    }
}

// single-block exclusive scan of bucket counts (K <= 4096)
__global__ __launch_bounds__(1024)
void bucket_scan(const int* __restrict__ bcnt, int* __restrict__ bofs,
                 int* __restrict__ bcur, int K) {
    __shared__ int s[1024];
    const int t = threadIdx.x;
    const int base = t * 4;
    int c[4];
#pragma unroll
    for (int j = 0; j < 4; ++j) c[j] = (base + j < K) ? bcnt[base + j] : 0;
    const int tot = c[0] + c[1] + c[2] + c[3];
    s[t] = tot;
    __syncthreads();
    for (int off = 1; off < 1024; off <<= 1) {
        int v = (t >= off) ? s[t - off] : 0;
        __syncthreads();
        s[t] += v;
        __syncthreads();
    }
    int run = s[t] - tot;   // exclusive prefix
#pragma unroll
    for (int j = 0; j < 4; ++j) {
        int idx = base + j;
        if (idx < K) { bofs[idx] = run; bcur[idx] = run; run += c[j]; }
    }
    if (t == 1023) bofs[K] = s[1023];
}

// scatter each edge into its dst-bucket as packed (src<<6)|(dst&63)
__global__ void scatter_kernel(const int* __restrict__ src, const int* __restrict__ dst,
                               int* __restrict__ bcur, u32* __restrict__ pairs, int E) {
    for (int i = blockIdx.x * blockDim.x + threadIdx.x; i < E; i += gridDim.x * blockDim.x) {
        int d = dst[i];
        int p = atomicAdd(&bcur[d >> 6], 1);
        pairs[p] = ((u32)src[i] << 6) | (u32)(d & 63);
    }
}

// per-bucket in-degree via LDS histogram (64 local nodes)
__global__ __launch_bounds__(256)
void bucket_count_in(const u32* __restrict__ pairs, const int* __restrict__ bofs,
                     int* __restrict__ cnt_in, int N) {
    const int b = blockIdx.x;
    __shared__ int lc[64];
    if (threadIdx.x < 64) lc[threadIdx.x] = 0;
    __syncthreads();
    const int s0 = bofs[b], s1 = bofs[b + 1];
    for (int i = s0 + threadIdx.x; i < s1; i += 256)
        atomicAdd(&lc[pairs[i] & 63], 1);
    __syncthreads();
    const int node = b * 64 + threadIdx.x;
    if (threadIdx.x < 64 && node < N) cnt_in[node] = lc[threadIdx.x];
}

// ---- device-wide exclusive scan of cnt_in (3 passes, 1024 elems/block) ----

__global__ __launch_bounds__(256)
void scan_pass1(const int* __restrict__ cnt_in, int* __restrict__ blocksum, int N) {
    const int b = blockIdx.x, t = threadIdx.x;
    const int base = b * 1024 + t * 4;
    int s = 0;
#pragma unroll
    for (int j = 0; j < 4; ++j) {
        int idx = base + j;
        if (idx < N) s += cnt_in[idx];
    }
#pragma unroll
    for (int off = 32; off >= 1; off >>= 1) s += __shfl_xor(s, off);
    __shared__ int wsum[4];
    if ((t & 63) == 0) wsum[t >> 6] = s;
    __syncthreads();
    if (t == 0) blocksum[b] = wsum[0] + wsum[1] + wsum[2] + wsum[3];
}

__global__ __launch_bounds__(128)
void scan_pass2(const int* __restrict__ blocksum, int* __restrict__ blockoff,
                int* __restrict__ row_start, int N, int nb) {
    __shared__ int s[128];
    const int t = threadIdx.x;
    int v = (t < nb) ? blocksum[t] : 0;
    s[t] = v;
    __syncthreads();
    for (int off = 1; off < 128; off <<= 1) {
        int x = (t >= off) ? s[t - off] : 0;
        __syncthreads();
        s[t] += x;
        __syncthreads();
    }
    if (t < nb) blockoff[t] = s[t] - v;     // exclusive
    if (t == 127) row_start[N] = s[127];    // total (=E)
}

__global__ __launch_bounds__(256)
void scan_pass3(const int* __restrict__ cnt_in, const int* __restrict__ cnt_out,
                const int* __restrict__ blockoff,
                int* __restrict__ row_start,
                float* __restrict__ iso, float* __restrict__ isi, int N) {
    __shared__ int ssum[256];
    const int b = blockIdx.x, t = threadIdx.x;
    const int base = b * 1024 + t * 4;
    int c[4];
#pragma unroll
    for (int j = 0; j < 4; ++j) {
        int idx = base + j;
        c[j] = (idx < N) ? cnt_in[idx] : 0;
    }
    const int tot = c[0] + c[1] + c[2] + c[3];
    ssum[t] = tot;
    __syncthreads();
    for (int off = 1; off < 256; off <<= 1) {
        int v = (t >= off) ? ssum[t - off] : 0;
        __syncthreads();
        ssum[t] += v;
        __syncthreads();
    }
    int run = blockoff[b] + ssum[t] - tot;  // exclusive prefix for this thread
#pragma unroll
    for (int j = 0; j < 4; ++j) {
        int idx = base + j;
        if (idx < N) {
            row_start[idx] = run;
            run += c[j];
            int di = c[j] < 1 ? 1 : c[j];
            int co = cnt_out[idx];
            int dd = co < 1 ? 1 : co;
            isi[idx] = rsqrtf((float)di);
            iso[idx] = rsqrtf((float)dd);
        }
    }
}

// per-bucket CSR fill: LDS cursors, contiguous ~4KB csr region per bucket
__global__ __launch_bounds__(256)
void bucket_fill(const u32* __restrict__ pairs, const int* __restrict__ bofs,
                 const int* __restrict__ row_start, int* __restrict__ csr, int N) {
    const int b = blockIdx.x;
    __shared__ int lcur[64];
    if (threadIdx.x < 64) {
        int node = b * 64 + threadIdx.x;
        lcur[threadIdx.x] = (node < N) ? row_start[node] : 0;
    }
    __syncthreads();
    const int s0 = bofs[b], s1 = bofs[b + 1];
    for (int i = s0 + threadIdx.x; i < s1; i += 256) {
        u32 pr = pairs[i];
        int p = atomicAdd(&lcur[pr & 63], 1);
        csr[p] = (int)(pr >> 6);
    }
}

// ---------------------------------------------------------------- GEMM
// H[N x C] (bf16) = (X[N x 128] * iso[:,None]) @ W[128 x C]
template <int C>
__global__ __launch_bounds__(256)
void gemm_kernel(const float* __restrict__ X, const float* __restrict__ W,
                 const float* __restrict__ iso, u16* __restrict__ H, int N) {
    extern __shared__ float lds[];
    float* Ws = lds;               // 128*C
    float* Xs = lds + 128 * C;     // 128 rows * PAD
    const int PAD = 130;
    const int t = threadIdx.x;
    const int row0 = blockIdx.x * 128;

    for (int i = t * 4; i < 128 * C; i += 256 * 4) {
        *(float4*)(Ws + i) = *(const float4*)(W + i);
    }
    for (int i = t; i < 128 * 32; i += 256) {
        int r  = i >> 5;
        int kv = (i & 31) << 2;
        int gr = row0 + r;
        if (gr >= N) gr = N - 1;
        float sc = iso[gr];
        float4 x = *(const float4*)(X + (size_t)gr * 128 + kv);
        float* d = Xs + r * PAD + kv;
        d[0] = x.x * sc; d[1] = x.y * sc; d[2] = x.z * sc; d[3] = x.w * sc;
    }
    __syncthreads();

    const int CPT = C / 16;
    const int tc = t & 15, tr = t >> 4;
    const int r0 = tr * 8, c0 = tc * CPT;

    float acc[8][CPT];
#pragma unroll
    for (int i = 0; i < 8; ++i)
#pragma unroll
        for (int j = 0; j < CPT; ++j) acc[i][j] = 0.f;

    for (int k = 0; k < 128; ++k) {
        float a[8];
#pragma unroll
        for (int i = 0; i < 8; ++i) a[i] = Xs[(r0 + i) * PAD + k];
        float b[CPT];
#pragma unroll
        for (int j = 0; j < CPT; ++j) b[j] = Ws[k * C + c0 + j];
#pragma unroll
        for (int i = 0; i < 8; ++i)
#pragma unroll
            for (int j = 0; j < CPT; ++j) acc[i][j] = fmaf(a[i], b[j], acc[i][j]);
    }

#pragma unroll
    for (int i = 0; i < 8; ++i) {
        int gr = row0 + r0 + i;
        if (gr < N) {
            alignas(16) u16 u[CPT];
#pragma unroll
            for (int j = 0; j < CPT; ++j) {
                __hip_bfloat16 h = __float2bfloat16(acc[i][j]);   // RNE
                u[j] = *(u16*)&h;
            }
            if (CPT == 8) {
                *(uint4*)(H + (size_t)gr * C + c0) = *(uint4*)u;
            } else {
                *(uint2*)(H + (size_t)gr * C + c0) = *(uint2*)u;
            }
        }
    }
}

// ---------------------------------------------------------------- aggregation
template <int C, bool RELU, bool FINAL>
__global__ __launch_bounds__(256)
void agg_kernel(const u16* __restrict__ H, const int* __restrict__ row_start,
                const int* __restrict__ csr_src, const float* __restrict__ isi,
                const float* __restrict__ bias, float* __restrict__ Out, int N) {
    const int wid  = (int)((blockIdx.x * (size_t)blockDim.x + threadIdx.x) >> 6);
    const int lane = threadIdx.x & 63;
    if (wid >= N) return;
    const int rs = row_start[wid];
    const int re = row_start[wid + 1];
    const float sc = isi[wid];

    if (C == 128) {
        float ax = 0.f, ay = 0.f;
        int e = rs;
        while (e < re) {
            int nloc = re - e;
            if (nloc > 64) nloc = 64;
            int idx = 0;
            if (lane < nloc) idx = csr_src[e + lane];
            int j = 0;
            for (; j + 4 <= nloc; j += 4) {
                int s0 = __builtin_amdgcn_readlane(idx, j);
                int s1 = __builtin_amdgcn_readlane(idx, j + 1);
                int s2 = __builtin_amdgcn_readlane(idx, j + 2);
                int s3 = __builtin_amdgcn_readlane(idx, j + 3);
                u32 v0 = *(const u32*)(H + (size_t)s0 * 128 + lane * 2);
                u32 v1 = *(const u32*)(H + (size_t)s1 * 128 + lane * 2);
                u32 v2 = *(const u32*)(H + (size_t)s2 * 128 + lane * 2);
                u32 v3 = *(const u32*)(H + (size_t)s3 * 128 + lane * 2);
                ax += __uint_as_float(v0 << 16); ay += __uint_as_float(v0 & 0xffff0000u);
                ax += __uint_as_float(v1 << 16); ay += __uint_as_float(v1 & 0xffff0000u);
                ax += __uint_as_float(v2 << 16); ay += __uint_as_float(v2 & 0xffff0000u);
                ax += __uint_as_float(v3 << 16); ay += __uint_as_float(v3 & 0xffff0000u);
            }
            for (; j < nloc; ++j) {
                int s0 = __builtin_amdgcn_readlane(idx, j);
                u32 v0 = *(const u32*)(H + (size_t)s0 * 128 + lane * 2);
                ax += __uint_as_float(v0 << 16); ay += __uint_as_float(v0 & 0xffff0000u);
            }
            e += nloc;
        }
        float2 b = *(const float2*)(bias + lane * 2);
        float o0 = ax * sc + b.x;
        float o1 = ay * sc + b.y;
        if (RELU) { o0 = fmaxf(o0, 0.f); o1 = fmaxf(o1, 0.f); }
        float2 o = make_float2(o0, o1);
        *(float2*)(Out + (size_t)wid * 128 + lane * 2) = o;
    } else {
        float a = 0.f;
        int e = rs;
        while (e < re) {
            int nloc = re - e;
            if (nloc > 64) nloc = 64;
            int idx = 0;
            if (lane < nloc) idx = csr_src[e + lane];
            int j = 0;
            for (; j + 4 <= nloc; j += 4) {
                int s0 = __builtin_amdgcn_readlane(idx, j);
                int s1 = __builtin_amdgcn_readlane(idx, j + 1);
                int s2 = __builtin_amdgcn_readlane(idx, j + 2);
                int s3 = __builtin_amdgcn_readlane(idx, j + 3);
                u32 v0 = H[(size_t)s0 * 64 + lane];
                u32 v1 = H[(size_t)s1 * 64 + lane];
                u32 v2 = H[(size_t)s2 * 64 + lane];
                u32 v3 = H[(size_t)s3 * 64 + lane];
                a += __uint_as_float(v0 << 16);
                a += __uint_as_float(v1 << 16);
                a += __uint_as_float(v2 << 16);
                a += __uint_as_float(v3 << 16);
            }
            for (; j < nloc; ++j) {
                int s0 = __builtin_amdgcn_readlane(idx, j);
                a += __uint_as_float((u32)H[(size_t)s0 * 64 + lane] << 16);
            }
            e += nloc;
        }
        float v = a * sc + bias[lane];
        if (FINAL) {
            float m = v;
#pragma unroll
            for (int off = 32; off >= 1; off >>= 1) m = fmaxf(m, __shfl_xor(m, off));
            float ex = expf(v - m);
            float ss = ex;
#pragma unroll
            for (int off = 32; off >= 1; off >>= 1) ss += __shfl_xor(ss, off);
            v = (v - m) - logf(ss);
        }
        if (RELU) v = fmaxf(v, 0.f);
        Out[(size_t)wid * 64 + lane] = v;
    }
}

// ---------------------------------------------------------------- launch

extern "C" void kernel_launch(void* const* d_in, const int* in_sizes, int n_in,
                              void* d_out, int out_size, void* d_ws, size_t ws_size,
                              hipStream_t stream) {
    const float* features = (const float*)d_in[0];
    const int*   src      = (const int*)d_in[1];
    const int*   dst      = (const int*)d_in[2];
    const float* W1       = (const float*)d_in[3];
    const float* b1       = (const float*)d_in[4];
    const float* W2       = (const float*)d_in[5];
    const float* b2       = (const float*)d_in[6];
    const float* W3       = (const float*)d_in[7];
    const float* b3       = (const float*)d_in[8];
    float*       out      = (float*)d_out;

    const int N = in_sizes[0] / IN_C;   // 100000
    const int E = in_sizes[1];          // 1600000
    const int K = (N + 63) >> 6;        // 1563 coarse buckets

    char* ws = (char*)d_ws;
    const size_t SLOT = 400128;                         // >= (N+1)*4, 128B-aligned
    int*   cnt_out   = (int*)(ws + 0 * SLOT);
    int*   cnt_in    = (int*)(ws + 1 * SLOT);
    int*   row_start = (int*)(ws + 2 * SLOT);
    int*   bucket    = (int*)(ws + 3 * SLOT);           // bcnt K | bofs K+1 | bcur K
    float* iso       = (float*)(ws + 4 * SLOT);
    float* isi       = (float*)(ws + 5 * SLOT);
    int*   csr       = (int*)(ws + 6 * SLOT);                           // E ints
    u16*   Hb        = (u16*)(ws + 6 * SLOT + 6400000);                 // N*128 bf16 (25.6MB used of 51.2MB slot)
    u32*   pairs     = (u32*)(ws + 6 * SLOT + 6400000 + 26000000);      // E u32 (6.4MB)
    float* act       = (float*)(ws + 6 * SLOT + 6400000 + 51200000);    // N*128 f32
    int*   blocksum  = (int*)(ws + 6 * SLOT + 6400000 + 2 * 51200000);  // 128 ints
    int*   blockoff  = blocksum + 128;                                  // 128 ints

    int* bcnt = bucket;
    int* bofs = bucket + K;
    int* bcur = bucket + 2 * K + 1;

    // ---- CSR build via coarse radix bucketing ----
    const int nb = (N + 1023) / 1024;   // scan blocks (98 for N=100000, <=128)
    zero_kernel<<<(N + K + 255) / 256, 256, 0, stream>>>(cnt_out, N + K);  // cnt_out | (gap) ...
    zero_kernel<<<(K + 255) / 256, 256, 0, stream>>>(bcnt, K);
    count_kernel<<<1024, 256, 0, stream>>>(src, dst, cnt_out, bcnt, E);
    bucket_scan<<<1, 1024, 0, stream>>>(bcnt, bofs, bcur, K);
    scatter_kernel<<<1024, 256, 0, stream>>>(src, dst, bcur, pairs, E);
    bucket_count_in<<<K, 256, 0, stream>>>(pairs, bofs, cnt_in, N);
    scan_pass1<<<nb, 256, 0, stream>>>(cnt_in, blocksum, N);
    scan_pass2<<<1, 128, 0, stream>>>(blocksum, blockoff, row_start, N, nb);
    scan_pass3<<<nb, 256, 0, stream>>>(cnt_in, cnt_out, blockoff, row_start, iso, isi, N);
    bucket_fill<<<K, 256, 0, stream>>>(pairs, bofs, row_start, csr, N);

    // ---- 3-layer GCN ----
    const int gblocks = (N + 127) / 128;
    const size_t lds128 = (size_t)(128 * 128 + 128 * 130) * sizeof(float); // 129 KiB
    const size_t lds64  = (size_t)(128 * 64  + 128 * 130) * sizeof(float); //  97 KiB
    const int ablocks = (int)(((size_t)N * 64 + 255) / 256);

    // layer 1
    gemm_kernel<128><<<gblocks, 256, lds128, stream>>>(features, W1, iso, Hb, N);
    agg_kernel<128, true, false><<<ablocks, 256, 0, stream>>>(Hb, row_start, csr, isi, b1, act, N);
    // layer 2
    gemm_kernel<128><<<gblocks, 256, lds128, stream>>>(act, W2, iso, Hb, N);
    agg_kernel<128, true, false><<<ablocks, 256, 0, stream>>>(Hb, row_start, csr, isi, b2, act, N);
    // layer 3 + fused log_softmax
    gemm_kernel<64><<<gblocks, 256, lds64, stream>>>(act, W3, iso, Hb, N);
    agg_kernel<64, false, true><<<ablocks, 256, 0, stream>>>(Hb, row_start, csr, isi, b3, out, N);
}

// Round 6
// 561.133 us; speedup vs baseline: 1.8436x; 1.8436x over previous
//
#include <hip/hip_runtime.h>
#include <hip/hip_bf16.h>

#define IN_C 128
#define HID_C 128
#define OUT_C 64

typedef unsigned short u16;
typedef unsigned int   u32;

// ============================ CSR build: contention-free radix partition
// Buckets of 256 nodes: bucket = v>>8, K = ceil(N/256). NB partition blocks.
// BH layout is bucket-major: BH[k*NB + b] so a flat exclusive scan yields
// per-block per-bucket write offsets directly.

__global__ __launch_bounds__(256)
void part_hist(const int* __restrict__ keys, int* __restrict__ bh,
               int E, int K, int NB) {
    const int b = blockIdx.x;
    extern __shared__ int lh[];                 // K ints
    for (int i = threadIdx.x; i < K; i += 256) lh[i] = 0;
    __syncthreads();
    const int lo = (int)((long long)E * b / NB);
    const int hi = (int)((long long)E * (b + 1) / NB);
    for (int i = lo + threadIdx.x; i < hi; i += 256)
        atomicAdd(&lh[keys[i] >> 8], 1);        // LDS atomic, 391 bins
    __syncthreads();
    for (int k = threadIdx.x; k < K; k += 256)
        bh[k * NB + b] = lh[k];
}

template <bool PACK>
__global__ __launch_bounds__(256)
void part_scatter(const int* __restrict__ keys, const int* __restrict__ other,
                  const int* __restrict__ ofs, u32* __restrict__ out,
                  int E, int K, int NB) {
    const int b = blockIdx.x;
    extern __shared__ int lcur[];               // K ints
    for (int k = threadIdx.x; k < K; k += 256) lcur[k] = ofs[k * NB + b];
    __syncthreads();
    const int lo = (int)((long long)E * b / NB);
    const int hi = (int)((long long)E * (b + 1) / NB);
    for (int i = lo + threadIdx.x; i < hi; i += 256) {
        int key = keys[i];
        int p = atomicAdd(&lcur[key >> 8], 1);  // LDS atomic
        out[p] = PACK ? (((u32)other[i] << 8) | (u32)(key & 255)) : (u32)key;
    }
}

// per-bucket degree count from partitioned values (low 8 bits = local node)
__global__ __launch_bounds__(256)
void bucket_count(const u32* __restrict__ pairs, const int* __restrict__ ofs,
                  int* __restrict__ cnt, int N, int NB, int K, int cap) {
    const int k = blockIdx.x;
    __shared__ int lc[256];
    lc[threadIdx.x] = 0;
    __syncthreads();
    const int s0 = ofs[k * NB];
    const int s1 = (k == K - 1) ? cap : ofs[(k + 1) * NB];
    for (int i = s0 + threadIdx.x; i < s1; i += 256)
        atomicAdd(&lc[pairs[i] & 255], 1);
    __syncthreads();
    const int node = k * 256 + threadIdx.x;
    if (node < N) cnt[node] = lc[threadIdx.x];
}

// per-bucket CSR fill: LDS cursors, contiguous ~16KB csr region per bucket
__global__ __launch_bounds__(256)
void bucket_fill(const u32* __restrict__ pairs, const int* __restrict__ ofs,
                 const int* __restrict__ row_start, int* __restrict__ csr,
                 int N, int NB, int K, int E) {
    const int k = blockIdx.x;
    __shared__ int lcur[256];
    const int node = k * 256 + threadIdx.x;
    lcur[threadIdx.x] = (node < N) ? row_start[node] : 0;
    __syncthreads();
    const int s0 = ofs[k * NB];
    const int s1 = (k == K - 1) ? E : ofs[(k + 1) * NB];
    for (int i = s0 + threadIdx.x; i < s1; i += 256) {
        u32 pr = pairs[i];
        int p = atomicAdd(&lcur[pr & 255], 1);
        csr[p] = (int)(pr >> 8);
    }
}

// ============================ generic scans

// blocks of 1024 elems -> per-block sums
__global__ __launch_bounds__(256)
void scan_pass1(const int* __restrict__ in, int* __restrict__ blocksum, int M) {
    const int b = blockIdx.x, t = threadIdx.x;
    const int base = b * 1024 + t * 4;
    int s = 0;
#pragma unroll
    for (int j = 0; j < 4; ++j) {
        int idx = base + j;
        if (idx < M) s += in[idx];
    }
#pragma unroll
    for (int off = 32; off >= 1; off >>= 1) s += __shfl_xor(s, off);
    __shared__ int wsum[4];
    if ((t & 63) == 0) wsum[t >> 6] = s;
    __syncthreads();
    if (t == 0) blocksum[b] = wsum[0] + wsum[1] + wsum[2] + wsum[3];
}

// in-place exclusive scan of <=1024 block sums
__global__ __launch_bounds__(1024)
void scan_g2(int* __restrict__ a, int nb) {
    __shared__ int s[1024];
    const int t = threadIdx.x;
    int v = (t < nb) ? a[t] : 0;
    s[t] = v;
    __syncthreads();
    for (int off = 1; off < 1024; off <<= 1) {
        int x = (t >= off) ? s[t - off] : 0;
        __syncthreads();
        s[t] += x;
        __syncthreads();
    }
    if (t < nb) a[t] = s[t] - v;    // exclusive
}

// generic pass3: write full exclusive scan
__global__ __launch_bounds__(256)
void scan_g3(const int* __restrict__ in, const int* __restrict__ blockoff,
             int* __restrict__ out, int M) {
    __shared__ int ssum[256];
    const int b = blockIdx.x, t = threadIdx.x;
    const int base = b * 1024 + t * 4;
    int c[4];
#pragma unroll
    for (int j = 0; j < 4; ++j) {
        int idx = base + j;
        c[j] = (idx < M) ? in[idx] : 0;
    }
    const int tot = c[0] + c[1] + c[2] + c[3];
    ssum[t] = tot;
    __syncthreads();
    for (int off = 1; off < 256; off <<= 1) {
        int v = (t >= off) ? ssum[t - off] : 0;
        __syncthreads();
        ssum[t] += v;
        __syncthreads();
    }
    int run = blockoff[b] + ssum[t] - tot;
#pragma unroll
    for (int j = 0; j < 4; ++j) {
        int idx = base + j;
        if (idx < M) { out[idx] = run; run += c[j]; }
    }
}

// node pass3: row_start + iso/isi fused
__global__ __launch_bounds__(256)
void scan_pass3n(const int* __restrict__ cnt_in, const int* __restrict__ cnt_out,
                 const int* __restrict__ blockoff, int* __restrict__ row_start,
                 float* __restrict__ iso, float* __restrict__ isi, int N, int E) {
    __shared__ int ssum[256];
    const int b = blockIdx.x, t = threadIdx.x;
    const int base = b * 1024 + t * 4;
    int c[4];
#pragma unroll
    for (int j = 0; j < 4; ++j) {
        int idx = base + j;
        c[j] = (idx < N) ? cnt_in[idx] : 0;
    }
    const int tot = c[0] + c[1] + c[2] + c[3];
    ssum[t] = tot;
    __syncthreads();
    for (int off = 1; off < 256; off <<= 1) {
        int v = (t >= off) ? ssum[t - off] : 0;
        __syncthreads();
        ssum[t] += v;
        __syncthreads();
    }
    int run = blockoff[b] + ssum[t] - tot;
#pragma unroll
    for (int j = 0; j < 4; ++j) {
        int idx = base + j;
        if (idx < N) {
            row_start[idx] = run;
            run += c[j];
            int di = c[j] < 1 ? 1 : c[j];
            int co = cnt_out[idx];
            int dd = co < 1 ? 1 : co;
            isi[idx] = rsqrtf((float)di);
            iso[idx] = rsqrtf((float)dd);
        }
    }
    if (b == 0 && t == 0) row_start[N] = E;
}

// ============================ GEMM: H[NxC] (bf16) = (X * iso[:,None]) @ W
template <int C>
__global__ __launch_bounds__(256)
void gemm_kernel(const float* __restrict__ X, const float* __restrict__ W,
                 const float* __restrict__ iso, u16* __restrict__ H, int N) {
    extern __shared__ float lds[];
    float* Ws = lds;               // 128*C
    float* Xs = lds + 128 * C;     // 128 rows * PAD
    const int PAD = 130;
    const int t = threadIdx.x;
    const int row0 = blockIdx.x * 128;

    for (int i = t * 4; i < 128 * C; i += 256 * 4) {
        *(float4*)(Ws + i) = *(const float4*)(W + i);
    }
    for (int i = t; i < 128 * 32; i += 256) {
        int r  = i >> 5;
        int kv = (i & 31) << 2;
        int gr = row0 + r;
        if (gr >= N) gr = N - 1;
        float sc = iso[gr];
        float4 x = *(const float4*)(X + (size_t)gr * 128 + kv);
        float* d = Xs + r * PAD + kv;
        d[0] = x.x * sc; d[1] = x.y * sc; d[2] = x.z * sc; d[3] = x.w * sc;
    }
    __syncthreads();

    const int CPT = C / 16;
    const int tc = t & 15, tr = t >> 4;
    const int r0 = tr * 8, c0 = tc * CPT;

    float acc[8][CPT];
#pragma unroll
    for (int i = 0; i < 8; ++i)
#pragma unroll
        for (int j = 0; j < CPT; ++j) acc[i][j] = 0.f;

    for (int k = 0; k < 128; ++k) {
        float a[8];
#pragma unroll
        for (int i = 0; i < 8; ++i) a[i] = Xs[(r0 + i) * PAD + k];
        float b[CPT];
#pragma unroll
        for (int j = 0; j < CPT; ++j) b[j] = Ws[k * C + c0 + j];
#pragma unroll
        for (int i = 0; i < 8; ++i)
#pragma unroll
            for (int j = 0; j < CPT; ++j) acc[i][j] = fmaf(a[i], b[j], acc[i][j]);
    }

#pragma unroll
    for (int i = 0; i < 8; ++i) {
        int gr = row0 + r0 + i;
        if (gr < N) {
            alignas(16) u16 u[CPT];
#pragma unroll
            for (int j = 0; j < CPT; ++j) {
                __hip_bfloat16 h = __float2bfloat16(acc[i][j]);   // RNE
                u[j] = *(u16*)&h;
            }
            if (CPT == 8) {
                *(uint4*)(H + (size_t)gr * C + c0) = *(uint4*)u;
            } else {
                *(uint2*)(H + (size_t)gr * C + c0) = *(uint2*)u;
            }
        }
    }
}

// ============================ aggregation (MLP x4 gather)
template <int C, bool RELU, bool FINAL>
__global__ __launch_bounds__(256)
void agg_kernel(const u16* __restrict__ H, const int* __restrict__ row_start,
                const int* __restrict__ csr_src, const float* __restrict__ isi,
                const float* __restrict__ bias, float* __restrict__ Out, int N) {
    const int wid  = (int)((blockIdx.x * (size_t)blockDim.x + threadIdx.x) >> 6);
    const int lane = threadIdx.x & 63;
    if (wid >= N) return;
    const int rs = row_start[wid];
    const int re = row_start[wid + 1];
    const float sc = isi[wid];

    if (C == 128) {
        float ax = 0.f, ay = 0.f;
        int e = rs;
        while (e < re) {
            int nloc = re - e;
            if (nloc > 64) nloc = 64;
            int idx = 0;
            if (lane < nloc) idx = csr_src[e + lane];
            int j = 0;
            for (; j + 4 <= nloc; j += 4) {
                int s0 = __builtin_amdgcn_readlane(idx, j);
                int s1 = __builtin_amdgcn_readlane(idx, j + 1);
                int s2 = __builtin_amdgcn_readlane(idx, j + 2);
                int s3 = __builtin_amdgcn_readlane(idx, j + 3);
                u32 v0 = *(const u32*)(H + (size_t)s0 * 128 + lane * 2);
                u32 v1 = *(const u32*)(H + (size_t)s1 * 128 + lane * 2);
                u32 v2 = *(const u32*)(H + (size_t)s2 * 128 + lane * 2);
                u32 v3 = *(const u32*)(H + (size_t)s3 * 128 + lane * 2);
                ax += __uint_as_float(v0 << 16); ay += __uint_as_float(v0 & 0xffff0000u);
                ax += __uint_as_float(v1 << 16); ay += __uint_as_float(v1 & 0xffff0000u);
                ax += __uint_as_float(v2 << 16); ay += __uint_as_float(v2 & 0xffff0000u);
                ax += __uint_as_float(v3 << 16); ay += __uint_as_float(v3 & 0xffff0000u);
            }
            for (; j < nloc; ++j) {
                int s0 = __builtin_amdgcn_readlane(idx, j);
                u32 v0 = *(const u32*)(H + (size_t)s0 * 128 + lane * 2);
                ax += __uint_as_float(v0 << 16); ay += __uint_as_float(v0 & 0xffff0000u);
            }
            e += nloc;
        }
        float2 b = *(const float2*)(bias + lane * 2);
        float o0 = ax * sc + b.x;
        float o1 = ay * sc + b.y;
        if (RELU) { o0 = fmaxf(o0, 0.f); o1 = fmaxf(o1, 0.f); }
        float2 o = make_float2(o0, o1);
        *(float2*)(Out + (size_t)wid * 128 + lane * 2) = o;
    } else {
        float a = 0.f;
        int e = rs;
        while (e < re) {
            int nloc = re - e;
            if (nloc > 64) nloc = 64;
            int idx = 0;
            if (lane < nloc) idx = csr_src[e + lane];
            int j = 0;
            for (; j + 4 <= nloc; j += 4) {
                int s0 = __builtin_amdgcn_readlane(idx, j);
                int s1 = __builtin_amdgcn_readlane(idx, j + 1);
                int s2 = __builtin_amdgcn_readlane(idx, j + 2);
                int s3 = __builtin_amdgcn_readlane(idx, j + 3);
                u32 v0 = H[(size_t)s0 * 64 + lane];
                u32 v1 = H[(size_t)s1 * 64 + lane];
                u32 v2 = H[(size_t)s2 * 64 + lane];
                u32 v3 = H[(size_t)s3 * 64 + lane];
                a += __uint_as_float(v0 << 16);
                a += __uint_as_float(v1 << 16);
                a += __uint_as_float(v2 << 16);
                a += __uint_as_float(v3 << 16);
            }
            for (; j < nloc; ++j) {
                int s0 = __builtin_amdgcn_readlane(idx, j);
                a += __uint_as_float((u32)H[(size_t)s0 * 64 + lane] << 16);
            }
            e += nloc;
        }
        float v = a * sc + bias[lane];
        if (FINAL) {
            float m = v;
#pragma unroll
            for (int off = 32; off >= 1; off >>= 1) m = fmaxf(m, __shfl_xor(m, off));
            float ex = expf(v - m);
            float ss = ex;
#pragma unroll
            for (int off = 32; off >= 1; off >>= 1) ss += __shfl_xor(ss, off);
            v = (v - m) - logf(ss);
        }
        if (RELU) v = fmaxf(v, 0.f);
        Out[(size_t)wid * 64 + lane] = v;
    }
}

// ============================ launch

extern "C" void kernel_launch(void* const* d_in, const int* in_sizes, int n_in,
                              void* d_out, int out_size, void* d_ws, size_t ws_size,
                              hipStream_t stream) {
    const float* features = (const float*)d_in[0];
    const int*   src      = (const int*)d_in[1];
    const int*   dst      = (const int*)d_in[2];
    const float* W1       = (const float*)d_in[3];
    const float* b1       = (const float*)d_in[4];
    const float* W2       = (const float*)d_in[5];
    const float* b2       = (const float*)d_in[6];
    const float* W3       = (const float*)d_in[7];
    const float* b3       = (const float*)d_in[8];
    float*       out      = (float*)d_out;

    const int N  = in_sizes[0] / IN_C;   // 100000
    const int E  = in_sizes[1];          // 1600000
    const int K  = (N + 255) >> 8;       // 391 buckets of 256 nodes
    const int NB = 256;                  // partition blocks
    const int M  = 2 * K * NB;           // concat hist size (dst part | src part)
    const int nbe = (M + 1023) / 1024;   // 196
    const int nb  = (N + 1023) / 1024;   // 98

    char* ws = (char*)d_ws;
    const size_t SLOT = 400128;          // >= (N+1)*4, 128B-aligned
    int*   cnt_out   = (int*)(ws + 0 * SLOT);
    int*   cnt_in    = (int*)(ws + 1 * SLOT);
    int*   row_start = (int*)(ws + 2 * SLOT);
    float* iso       = (float*)(ws + 3 * SLOT);
    float* isi       = (float*)(ws + 4 * SLOT);
    int*   blocksum  = (int*)(ws + 5 * SLOT);            // 128 ints
    int*   blockoff  = blocksum + 1024;                  // 128 ints
    int*   eblocksum = blocksum + 2048;                  // <=1024 ints
    int*   csr       = (int*)(ws + 6 * SLOT);            // E ints (6.4MB)
    char*  p        = ws + 6 * SLOT + 6400000;
    int*   BH        = (int*)p;                          // M ints (800KB)
    int*   OFS       = (int*)(p + 1000000);              // M ints (800KB)
    u32*   pairs     = (u32*)(p + 2000000);              // 2E u32 (12.8MB)
    u16*   Hb        = (u16*)(p + 2000000 + 12800000);   // N*128 bf16 (25.6MB)
    float* act       = (float*)(p + 2000000 + 12800000 + 25600000);  // N*128 f32

    const size_t ldsK = (size_t)K * sizeof(int);

    // ---- CSR build: deterministic two-array radix partition ----
    part_hist<<<NB, 256, ldsK, stream>>>(dst, BH,           E, K, NB);
    part_hist<<<NB, 256, ldsK, stream>>>(src, BH + K * NB,  E, K, NB);
    scan_pass1<<<nbe, 256, 0, stream>>>(BH, eblocksum, M);
    scan_g2<<<1, 1024, 0, stream>>>(eblocksum, nbe);
    scan_g3<<<nbe, 256, 0, stream>>>(BH, eblocksum, OFS, M);
    part_scatter<true ><<<NB, 256, ldsK, stream>>>(dst, src, OFS,          pairs, E, K, NB);
    part_scatter<false><<<NB, 256, ldsK, stream>>>(src, src, OFS + K * NB, pairs, E, K, NB);
    bucket_count<<<K, 256, 0, stream>>>(pairs, OFS,          cnt_in,  N, NB, K, E);
    bucket_count<<<K, 256, 0, stream>>>(pairs, OFS + K * NB, cnt_out, N, NB, K, 2 * E);
    scan_pass1<<<nb, 256, 0, stream>>>(cnt_in, blocksum, N);
    scan_g2<<<1, 1024, 0, stream>>>(blocksum, nb);
    scan_pass3n<<<nb, 256, 0, stream>>>(cnt_in, cnt_out, blocksum, row_start, iso, isi, N, E);
    bucket_fill<<<K, 256, 0, stream>>>(pairs, OFS, row_start, csr, N, NB, K, E);

    // ---- 3-layer GCN ----
    const int gblocks = (N + 127) / 128;
    const size_t lds128 = (size_t)(128 * 128 + 128 * 130) * sizeof(float); // 129 KiB
    const size_t lds64  = (size_t)(128 * 64  + 128 * 130) * sizeof(float); //  97 KiB
    const int ablocks = (int)(((size_t)N * 64 + 255) / 256);

    // layer 1
    gemm_kernel<128><<<gblocks, 256, lds128, stream>>>(features, W1, iso, Hb, N);
    agg_kernel<128, true, false><<<ablocks, 256, 0, stream>>>(Hb, row_start, csr, isi, b1, act, N);
    // layer 2
    gemm_kernel<128><<<gblocks, 256, lds128, stream>>>(act, W2, iso, Hb, N);
    agg_kernel<128, true, false><<<ablocks, 256, 0, stream>>>(Hb, row_start, csr, isi, b2, act, N);
    // layer 3 + fused log_softmax
    gemm_kernel<64><<<gblocks, 256, lds64, stream>>>(act, W3, iso, Hb, N);
    agg_kernel<64, false, true><<<ablocks, 256, 0, stream>>>(Hb, row_start, csr, isi, b3, out, N);
}

// Round 7
// 397.749 us; speedup vs baseline: 2.6009x; 1.4108x over previous
//
#include <hip/hip_runtime.h>
#include <hip/hip_bf16.h>

#define IN_C 128
#define HID_C 128
#define OUT_C 64

typedef unsigned short u16;
typedef unsigned int   u32;
typedef __attribute__((ext_vector_type(8))) short short8;
typedef __attribute__((ext_vector_type(4))) float f32x4;

__device__ __forceinline__ u16 bf16_bits(float x) {
    __hip_bfloat16 h = __float2bfloat16(x);   // RNE
    return *(u16*)&h;
}
__device__ __forceinline__ void split_hi_lo(float a, u16& hi, u16& lo) {
    __hip_bfloat16 h = __float2bfloat16(a);
    float hf = __bfloat162float(h);
    __hip_bfloat16 l = __float2bfloat16(a - hf);
    hi = *(u16*)&h; lo = *(u16*)&l;
}

// ============================ CSR build: contention-free radix partition
// Buckets of 256 nodes: bucket = v>>8, K = ceil(N/256). NB partition blocks.

__global__ __launch_bounds__(256)
void part_hist(const int* __restrict__ keys, int* __restrict__ bh,
               int E, int K, int NB) {
    const int b = blockIdx.x;
    extern __shared__ int lh[];                 // K ints
    for (int i = threadIdx.x; i < K; i += 256) lh[i] = 0;
    __syncthreads();
    const int lo = (int)((long long)E * b / NB);
    const int hi = (int)((long long)E * (b + 1) / NB);
    for (int i = lo + threadIdx.x; i < hi; i += 256)
        atomicAdd(&lh[keys[i] >> 8], 1);        // LDS atomic
    __syncthreads();
    for (int k = threadIdx.x; k < K; k += 256)
        bh[k * NB + b] = lh[k];
}

template <bool PACK>
__global__ __launch_bounds__(256)
void part_scatter(const int* __restrict__ keys, const int* __restrict__ other,
                  const int* __restrict__ ofs, u32* __restrict__ out,
                  int E, int K, int NB) {
    const int b = blockIdx.x;
    extern __shared__ int lcur[];               // K ints
    for (int k = threadIdx.x; k < K; k += 256) lcur[k] = ofs[k * NB + b];
    __syncthreads();
    const int lo = (int)((long long)E * b / NB);
    const int hi = (int)((long long)E * (b + 1) / NB);
    for (int i = lo + threadIdx.x; i < hi; i += 256) {
        int key = keys[i];
        int p = atomicAdd(&lcur[key >> 8], 1);  // LDS atomic
        out[p] = PACK ? (((u32)other[i] << 8) | (u32)(key & 255)) : (u32)key;
    }
}

__global__ __launch_bounds__(256)
void bucket_count(const u32* __restrict__ pairs, const int* __restrict__ ofs,
                  int* __restrict__ cnt, int N, int NB, int K, int cap) {
    const int k = blockIdx.x;
    __shared__ int lc[256];
    lc[threadIdx.x] = 0;
    __syncthreads();
    const int s0 = ofs[k * NB];
    const int s1 = (k == K - 1) ? cap : ofs[(k + 1) * NB];
    for (int i = s0 + threadIdx.x; i < s1; i += 256)
        atomicAdd(&lc[pairs[i] & 255], 1);
    __syncthreads();
    const int node = k * 256 + threadIdx.x;
    if (node < N) cnt[node] = lc[threadIdx.x];
}

__global__ __launch_bounds__(256)
void bucket_fill(const u32* __restrict__ pairs, const int* __restrict__ ofs,
                 const int* __restrict__ row_start, int* __restrict__ csr,
                 int N, int NB, int K, int E) {
    const int k = blockIdx.x;
    __shared__ int lcur[256];
    const int node = k * 256 + threadIdx.x;
    lcur[threadIdx.x] = (node < N) ? row_start[node] : 0;
    __syncthreads();
    const int s0 = ofs[k * NB];
    const int s1 = (k == K - 1) ? E : ofs[(k + 1) * NB];
    for (int i = s0 + threadIdx.x; i < s1; i += 256) {
        u32 pr = pairs[i];
        int p = atomicAdd(&lcur[pr & 255], 1);
        csr[p] = (int)(pr >> 8);
    }
}

// ============================ generic scans

__global__ __launch_bounds__(256)
void scan_pass1(const int* __restrict__ in, int* __restrict__ blocksum, int M) {
    const int b = blockIdx.x, t = threadIdx.x;
    const int base = b * 1024 + t * 4;
    int s = 0;
#pragma unroll
    for (int j = 0; j < 4; ++j) {
        int idx = base + j;
        if (idx < M) s += in[idx];
    }
#pragma unroll
    for (int off = 32; off >= 1; off >>= 1) s += __shfl_xor(s, off);
    __shared__ int wsum[4];
    if ((t & 63) == 0) wsum[t >> 6] = s;
    __syncthreads();
    if (t == 0) blocksum[b] = wsum[0] + wsum[1] + wsum[2] + wsum[3];
}

__global__ __launch_bounds__(1024)
void scan_g2(int* __restrict__ a, int nb) {
    __shared__ int s[1024];
    const int t = threadIdx.x;
    int v = (t < nb) ? a[t] : 0;
    s[t] = v;
    __syncthreads();
    for (int off = 1; off < 1024; off <<= 1) {
        int x = (t >= off) ? s[t - off] : 0;
        __syncthreads();
        s[t] += x;
        __syncthreads();
    }
    if (t < nb) a[t] = s[t] - v;    // exclusive
}

__global__ __launch_bounds__(256)
void scan_g3(const int* __restrict__ in, const int* __restrict__ blockoff,
             int* __restrict__ out, int M) {
    __shared__ int ssum[256];
    const int b = blockIdx.x, t = threadIdx.x;
    const int base = b * 1024 + t * 4;
    int c[4];
#pragma unroll
    for (int j = 0; j < 4; ++j) {
        int idx = base + j;
        c[j] = (idx < M) ? in[idx] : 0;
    }
    const int tot = c[0] + c[1] + c[2] + c[3];
    ssum[t] = tot;
    __syncthreads();
    for (int off = 1; off < 256; off <<= 1) {
        int v = (t >= off) ? ssum[t - off] : 0;
        __syncthreads();
        ssum[t] += v;
        __syncthreads();
    }
    int run = blockoff[b] + ssum[t] - tot;
#pragma unroll
    for (int j = 0; j < 4; ++j) {
        int idx = base + j;
        if (idx < M) { out[idx] = run; run += c[j]; }
    }
}

__global__ __launch_bounds__(256)
void scan_pass3n(const int* __restrict__ cnt_in, const int* __restrict__ cnt_out,
                 const int* __restrict__ blockoff, int* __restrict__ row_start,
                 float* __restrict__ iso, float* __restrict__ isi, int N, int E) {
    __shared__ int ssum[256];
    const int b = blockIdx.x, t = threadIdx.x;
    const int base = b * 1024 + t * 4;
    int c[4];
#pragma unroll
    for (int j = 0; j < 4; ++j) {
        int idx = base + j;
        c[j] = (idx < N) ? cnt_in[idx] : 0;
    }
    const int tot = c[0] + c[1] + c[2] + c[3];
    ssum[t] = tot;
    __syncthreads();
    for (int off = 1; off < 256; off <<= 1) {
        int v = (t >= off) ? ssum[t - off] : 0;
        __syncthreads();
        ssum[t] += v;
        __syncthreads();
    }
    int run = blockoff[b] + ssum[t] - tot;
#pragma unroll
    for (int j = 0; j < 4; ++j) {
        int idx = base + j;
        if (idx < N) {
            row_start[idx] = run;
            run += c[j];
            int di = c[j] < 1 ? 1 : c[j];
            int co = cnt_out[idx];
            int dd = co < 1 ? 1 : co;
            isi[idx] = rsqrtf((float)di);
            iso[idx] = rsqrtf((float)dd);
        }
    }
    if (b == 0 && t == 0) row_start[N] = E;
}

// ============================ GEMM input prep

// Wt[c][k] = bf16(W[k][c]); grid = C blocks, 128 threads (k)
__global__ __launch_bounds__(128)
void wt_prep(const float* __restrict__ W, u16* __restrict__ Wt, int C) {
    const int c = blockIdx.x, k = threadIdx.x;
    Wt[c * 128 + k] = bf16_bits(W[k * C + c]);
}

// layer-1 A planes: a = features * iso  ->  hi/lo bf16 planes
__global__ __launch_bounds__(256)
void x_prep(const float* __restrict__ X, const float* __restrict__ iso,
            u16* __restrict__ Ah, u16* __restrict__ Al, int total /*N*32*/) {
    for (int i = blockIdx.x * 256 + threadIdx.x; i < total; i += gridDim.x * 256) {
        int row = i >> 5;
        float s = iso[row];
        float4 x = ((const float4*)X)[i];
        u16 h0, l0, h1, l1, h2, l2, h3, l3;
        split_hi_lo(x.x * s, h0, l0);
        split_hi_lo(x.y * s, h1, l1);
        split_hi_lo(x.z * s, h2, l2);
        split_hi_lo(x.w * s, h3, l3);
        uint2 hp = make_uint2((u32)h0 | ((u32)h1 << 16), (u32)h2 | ((u32)h3 << 16));
        uint2 lp = make_uint2((u32)l0 | ((u32)l1 << 16), (u32)l2 | ((u32)l3 << 16));
        ((uint2*)Ah)[i] = hp;
        ((uint2*)Al)[i] = lp;
    }
}

// ============================ MFMA GEMM
// H[N x C] (bf16) = (Ah + Al)[N x 128] @ Wt^T, Wt is [C][128] bf16.
// Tile: 64 rows/block, 4 waves, each wave 16 rows x C cols, K=128 in 4 chunks.
template <int C>
__global__ __launch_bounds__(256)
void gemm_mfma(const u16* __restrict__ Ah, const u16* __restrict__ Al,
               const u16* __restrict__ Wt, u16* __restrict__ H, int N) {
    constexpr int NT = C / 16;
    __shared__ u16 sAh[64 * 136];   // +8 bf16 row pad: 272B stride -> 2-way banks
    __shared__ u16 sAl[64 * 136];
    const int t = threadIdx.x;
    const int row0 = blockIdx.x * 64;

    // stage 64 rows x 128 bf16 per plane (16B chunks)
    for (int c = t; c < 1024; c += 256) {
        int r = c >> 4, kc = c & 15;
        int gr = row0 + r;
        if (gr >= N) gr = N - 1;
        *(uint4*)(&sAh[r * 136 + kc * 8]) = *(const uint4*)(Ah + (size_t)gr * 128 + kc * 8);
        *(uint4*)(&sAl[r * 136 + kc * 8]) = *(const uint4*)(Al + (size_t)gr * 128 + kc * 8);
    }
    __syncthreads();

    const int wid = t >> 6, lane = t & 63;
    const int r0 = wid * 16;
    const int arow = r0 + (lane & 15);
    const int kb = (lane >> 4) * 8;          // k-offset within 32-chunk

    f32x4 acc[NT];
#pragma unroll
    for (int i = 0; i < NT; ++i) acc[i] = (f32x4){0.f, 0.f, 0.f, 0.f};

    const u16* wbase = Wt + (size_t)(lane & 15) * 128 + kb;

#pragma unroll
    for (int kk = 0; kk < 4; ++kk) {
        short8 ah = *(const short8*)(&sAh[arow * 136 + kk * 32 + kb]);
        short8 al = *(const short8*)(&sAl[arow * 136 + kk * 32 + kb]);
#pragma unroll
        for (int ct = 0; ct < NT; ++ct) {
            short8 bf = *(const short8*)(wbase + ct * 16 * 128 + kk * 32);
            acc[ct] = __builtin_amdgcn_mfma_f32_16x16x32_bf16(ah, bf, acc[ct], 0, 0, 0);
            acc[ct] = __builtin_amdgcn_mfma_f32_16x16x32_bf16(al, bf, acc[ct], 0, 0, 0);
        }
    }

    // epilogue: D col = lane&15, row = (lane>>4)*4 + reg
    const int rbase = row0 + r0 + (lane >> 4) * 4;
#pragma unroll
    for (int ct = 0; ct < NT; ++ct) {
        int gcol = ct * 16 + (lane & 15);
#pragma unroll
        for (int r = 0; r < 4; ++r) {
            int grow = rbase + r;
            if (grow < N) H[(size_t)grow * C + gcol] = bf16_bits(acc[ct][r]);
        }
    }
}

// ============================ aggregation (MLP x4 gather)

// layers 1-2: out = relu(agg*isi + b); emit hi/lo bf16 planes of (out*iso)
__global__ __launch_bounds__(256)
void agg_relu(const u16* __restrict__ H, const int* __restrict__ row_start,
              const int* __restrict__ csr_src, const float* __restrict__ isi,
              const float* __restrict__ iso, const float* __restrict__ bias,
              u16* __restrict__ Ah, u16* __restrict__ Al, int N) {
    const int wid  = (int)((blockIdx.x * (size_t)blockDim.x + threadIdx.x) >> 6);
    const int lane = threadIdx.x & 63;
    if (wid >= N) return;
    const int rs = row_start[wid];
    const int re = row_start[wid + 1];
    const float sc = isi[wid];

    float ax = 0.f, ay = 0.f;
    int e = rs;
    while (e < re) {
        int nloc = re - e;
        if (nloc > 64) nloc = 64;
        int idx = 0;
        if (lane < nloc) idx = csr_src[e + lane];
        int j = 0;
        for (; j + 4 <= nloc; j += 4) {
            int s0 = __builtin_amdgcn_readlane(idx, j);
            int s1 = __builtin_amdgcn_readlane(idx, j + 1);
            int s2 = __builtin_amdgcn_readlane(idx, j + 2);
            int s3 = __builtin_amdgcn_readlane(idx, j + 3);
            u32 v0 = *(const u32*)(H + (size_t)s0 * 128 + lane * 2);
            u32 v1 = *(const u32*)(H + (size_t)s1 * 128 + lane * 2);
            u32 v2 = *(const u32*)(H + (size_t)s2 * 128 + lane * 2);
            u32 v3 = *(const u32*)(H + (size_t)s3 * 128 + lane * 2);
            ax += __uint_as_float(v0 << 16); ay += __uint_as_float(v0 & 0xffff0000u);
            ax += __uint_as_float(v1 << 16); ay += __uint_as_float(v1 & 0xffff0000u);
            ax += __uint_as_float(v2 << 16); ay += __uint_as_float(v2 & 0xffff0000u);
            ax += __uint_as_float(v3 << 16); ay += __uint_as_float(v3 & 0xffff0000u);
        }
        for (; j < nloc; ++j) {
            int s0 = __builtin_amdgcn_readlane(idx, j);
            u32 v0 = *(const u32*)(H + (size_t)s0 * 128 + lane * 2);
            ax += __uint_as_float(v0 << 16); ay += __uint_as_float(v0 & 0xffff0000u);
        }
        e += nloc;
    }
    float2 b = *(const float2*)(bias + lane * 2);
    float o0 = fmaxf(ax * sc + b.x, 0.f);
    float o1 = fmaxf(ay * sc + b.y, 0.f);
    const float so = iso[wid];
    u16 h0, l0, h1, l1;
    split_hi_lo(o0 * so, h0, l0);
    split_hi_lo(o1 * so, h1, l1);
    ((u32*)Ah)[(size_t)wid * 64 + lane] = (u32)h0 | ((u32)h1 << 16);
    ((u32*)Al)[(size_t)wid * 64 + lane] = (u32)l0 | ((u32)l1 << 16);
}

// layer 3: C=64, fused log_softmax, f32 out
__global__ __launch_bounds__(256)
void agg_final(const u16* __restrict__ H, const int* __restrict__ row_start,
               const int* __restrict__ csr_src, const float* __restrict__ isi,
               const float* __restrict__ bias, float* __restrict__ Out, int N) {
    const int wid  = (int)((blockIdx.x * (size_t)blockDim.x + threadIdx.x) >> 6);
    const int lane = threadIdx.x & 63;
    if (wid >= N) return;
    const int rs = row_start[wid];
    const int re = row_start[wid + 1];
    const float sc = isi[wid];

    float a = 0.f;
    int e = rs;
    while (e < re) {
        int nloc = re - e;
        if (nloc > 64) nloc = 64;
        int idx = 0;
        if (lane < nloc) idx = csr_src[e + lane];
        int j = 0;
        for (; j + 4 <= nloc; j += 4) {
            int s0 = __builtin_amdgcn_readlane(idx, j);
            int s1 = __builtin_amdgcn_readlane(idx, j + 1);
            int s2 = __builtin_amdgcn_readlane(idx, j + 2);
            int s3 = __builtin_amdgcn_readlane(idx, j + 3);
            u32 v0 = H[(size_t)s0 * 64 + lane];
            u32 v1 = H[(size_t)s1 * 64 + lane];
            u32 v2 = H[(size_t)s2 * 64 + lane];
            u32 v3 = H[(size_t)s3 * 64 + lane];
            a += __uint_as_float(v0 << 16);
            a += __uint_as_float(v1 << 16);
            a += __uint_as_float(v2 << 16);
            a += __uint_as_float(v3 << 16);
        }
        for (; j < nloc; ++j) {
            int s0 = __builtin_amdgcn_readlane(idx, j);
            a += __uint_as_float((u32)H[(size_t)s0 * 64 + lane] << 16);
        }
        e += nloc;
    }
    float v = a * sc + bias[lane];
    float m = v;
#pragma unroll
    for (int off = 32; off >= 1; off >>= 1) m = fmaxf(m, __shfl_xor(m, off));
    float ex = expf(v - m);
    float ss = ex;
#pragma unroll
    for (int off = 32; off >= 1; off >>= 1) ss += __shfl_xor(ss, off);
    v = (v - m) - logf(ss);
    Out[(size_t)wid * 64 + lane] = v;
}

// ============================ launch

extern "C" void kernel_launch(void* const* d_in, const int* in_sizes, int n_in,
                              void* d_out, int out_size, void* d_ws, size_t ws_size,
                              hipStream_t stream) {
    const float* features = (const float*)d_in[0];
    const int*   src      = (const int*)d_in[1];
    const int*   dst      = (const int*)d_in[2];
    const float* W1       = (const float*)d_in[3];
    const float* b1       = (const float*)d_in[4];
    const float* W2       = (const float*)d_in[5];
    const float* b2       = (const float*)d_in[6];
    const float* W3       = (const float*)d_in[7];
    const float* b3       = (const float*)d_in[8];
    float*       out      = (float*)d_out;

    const int N  = in_sizes[0] / IN_C;   // 100000
    const int E  = in_sizes[1];          // 1600000
    const int K  = (N + 255) >> 8;       // 391 buckets of 256 nodes
    const int NB = 256;                  // partition blocks
    const int M  = 2 * K * NB;           // concat hist size (dst part | src part)
    const int nbe = (M + 1023) / 1024;
    const int nb  = (N + 1023) / 1024;

    char* ws = (char*)d_ws;
    const size_t SLOT = 400128;          // >= (N+1)*4, 128B-aligned
    int*   cnt_out   = (int*)(ws + 0 * SLOT);
    int*   cnt_in    = (int*)(ws + 1 * SLOT);
    int*   row_start = (int*)(ws + 2 * SLOT);
    float* iso       = (float*)(ws + 3 * SLOT);
    float* isi       = (float*)(ws + 4 * SLOT);
    int*   blocksum  = (int*)(ws + 5 * SLOT);
    int*   eblocksum = blocksum + 2048;
    int*   csr       = (int*)(ws + 6 * SLOT);            // E ints (6.4MB)
    char*  p         = ws + 6 * SLOT + 6400000;
    int*   BH        = (int*)p;                          // 800KB
    int*   OFS       = (int*)(p + 1000000);              // 800KB
    u32*   pairs     = (u32*)(p + 2000000);              // 2E u32 (12.8MB)
    u16*   Hb        = (u16*)(p + 14800000);             // N*128 bf16 (25.6MB)
    u16*   Ah        = (u16*)(p + 40400000);             // N*128 bf16 (25.6MB)
    u16*   Al        = (u16*)(p + 66000000);             // N*128 bf16 (25.6MB)
    u16*   Wt1       = (u16*)(p + 91600000);             // 128*128 bf16 (32KB)
    u16*   Wt2       = Wt1 + 128 * 128;
    u16*   Wt3       = Wt2 + 128 * 128;                  // 64*128 bf16

    const size_t ldsK = (size_t)K * sizeof(int);

    // ---- CSR build: deterministic two-array radix partition ----
    part_hist<<<NB, 256, ldsK, stream>>>(dst, BH,           E, K, NB);
    part_hist<<<NB, 256, ldsK, stream>>>(src, BH + K * NB,  E, K, NB);
    scan_pass1<<<nbe, 256, 0, stream>>>(BH, eblocksum, M);
    scan_g2<<<1, 1024, 0, stream>>>(eblocksum, nbe);
    scan_g3<<<nbe, 256, 0, stream>>>(BH, eblocksum, OFS, M);
    part_scatter<true ><<<NB, 256, ldsK, stream>>>(dst, src, OFS,          pairs, E, K, NB);
    part_scatter<false><<<NB, 256, ldsK, stream>>>(src, src, OFS + K * NB, pairs, E, K, NB);
    bucket_count<<<K, 256, 0, stream>>>(pairs, OFS,          cnt_in,  N, NB, K, E);
    bucket_count<<<K, 256, 0, stream>>>(pairs, OFS + K * NB, cnt_out, N, NB, K, 2 * E);
    scan_pass1<<<nb, 256, 0, stream>>>(cnt_in, blocksum, N);
    scan_g2<<<1, 1024, 0, stream>>>(blocksum, nb);
    scan_pass3n<<<nb, 256, 0, stream>>>(cnt_in, cnt_out, blocksum, row_start, iso, isi, N, E);
    bucket_fill<<<K, 256, 0, stream>>>(pairs, OFS, row_start, csr, N, NB, K, E);

    // ---- weight transpose + layer-1 input planes ----
    wt_prep<<<128, 128, 0, stream>>>(W1, Wt1, 128);
    wt_prep<<<128, 128, 0, stream>>>(W2, Wt2, 128);
    wt_prep<<<64,  128, 0, stream>>>(W3, Wt3, 64);
    x_prep<<<2048, 256, 0, stream>>>(features, iso, Ah, Al, N * 32);

    // ---- 3-layer GCN ----
    const int gblocks = (N + 63) / 64;
    const int ablocks = (int)(((size_t)N * 64 + 255) / 256);

    gemm_mfma<128><<<gblocks, 256, 0, stream>>>(Ah, Al, Wt1, Hb, N);
    agg_relu<<<ablocks, 256, 0, stream>>>(Hb, row_start, csr, isi, iso, b1, Ah, Al, N);
    gemm_mfma<128><<<gblocks, 256, 0, stream>>>(Ah, Al, Wt2, Hb, N);
    agg_relu<<<ablocks, 256, 0, stream>>>(Hb, row_start, csr, isi, iso, b2, Ah, Al, N);
    gemm_mfma<64><<<gblocks, 256, 0, stream>>>(Ah, Al, Wt3, Hb, N);
    agg_final<<<ablocks, 256, 0, stream>>>(Hb, row_start, csr, isi, b3, out, N);
}